// Round 5
// baseline (353.827 us; speedup 1.0000x reference)
//
#include <hip/hip_runtime.h>

// WhiteSoftmax: B=8192, C=64, O=128, 256 states, 256 vals.
// TA-throughput-bound redesign:
//   K_pack: add_table int32 -> u8 (8 MB ws).
//   K_walk: coalesced x -> packed bytes (LDS, swizzled) -> register walk of the
//           128-step state machine (global u8 gathers, irreducible) -> write
//           s[chain] + px bytes (64 MB) to ws.
//   K_out:  softmax_table staged in LDS as bf16 (128 KB); px chunks staged in
//           LDS; output gathers become ds_read_u16 (no TA cost); fully
//           coalesced px loads and float4 stores.

constexpr int O_DIM = 128;
constexpr long long NCHAINS = 8192LL * 64;        // 524288
constexpr int TAB_ENTRIES = 128 * 256 * 256;      // 8 MB u8

constexpr size_t WS_S   = 8u << 20;               // int32 s[NCHAINS] (2 MB)
constexpr size_t WS_PX  = 16u << 20;              // u8 px, 128 B/chain (64 MB)
constexpr size_t WS_FULL = 80u << 20;
constexpr size_t WS_MID  = 12u << 20;

typedef int   vi4 __attribute__((ext_vector_type(4)));
typedef float vf4 __attribute__((ext_vector_type(4)));

__global__ __launch_bounds__(256)
void pack_kernel(const int* __restrict__ t32, unsigned char* __restrict__ t8) {
    const int i = (blockIdx.x * 256 + threadIdx.x) * 4;
    vi4 v = *reinterpret_cast<const vi4*>(t32 + i);
    unsigned b = ((unsigned)v.x & 0xffu) | (((unsigned)v.y & 0xffu) << 8) |
                 (((unsigned)v.z & 0xffu) << 16) | (((unsigned)v.w & 0xffu) << 24);
    *reinterpret_cast<unsigned*>(t8 + i) = b;
}

// ---------------- walk kernel: 128 chains / 128 threads per block ----------
constexpr int ABLK = 128;

template <int WRITE_PX>
__global__ __launch_bounds__(ABLK)
void walk_kernel(const int* __restrict__ x, const unsigned char* __restrict__ t8,
                 int* __restrict__ s_out, unsigned* __restrict__ gpx) {
    __shared__ unsigned px_lds[ABLK * 32];
    const int t = threadIdx.x;
    const size_t chain0 = (size_t)blockIdx.x * ABLK;

    const vi4* xv = reinterpret_cast<const vi4*>(x + chain0 * O_DIM);
#pragma unroll 4
    for (int k = 0; k < 32; ++k) {
        const int idx = k * ABLK + t;
        vi4 v = __builtin_nontemporal_load(&xv[idx]);
        unsigned p = (unsigned)v.x | ((unsigned)v.y << 8) |
                     ((unsigned)v.z << 16) | ((unsigned)v.w << 24);
        px_lds[(idx >> 5) * 32 + ((idx & 31) ^ ((idx >> 5) & 31))] = p;
    }
    __syncthreads();

    unsigned px[32];
#pragma unroll
    for (int k = 0; k < 32; ++k)
        px[k] = px_lds[t * 32 + (k ^ (t & 31))];

    int s = 0;
#pragma unroll
    for (int j = 0; j < O_DIM; ++j) {
        unsigned xj = (px[j >> 2] >> ((j & 3) * 8)) & 0xffu;
        s = (int)t8[((unsigned)j << 16) | ((unsigned)s << 8) | xj];
    }
    s_out[chain0 + t] = s;

    if (WRITE_PX) {
#pragma unroll 4
        for (int k = 0; k < 32; ++k) {
            const int idx = k * ABLK + t;
            unsigned p = px_lds[(idx >> 5) * 32 + ((idx & 31) ^ ((idx >> 5) & 31))];
            __builtin_nontemporal_store(p, &gpx[chain0 * 32 + idx]);
        }
    }
}

// ---------------- output kernel: st in LDS as bf16 -------------------------
constexpr int BBLK = 512;
constexpr int CPB_B = 128;                         // chains per chunk
constexpr int GRID_B = 256;
constexpr int CHUNKS = (int)(NCHAINS / ((long long)GRID_B * CPB_B));  // 16

__device__ __forceinline__ unsigned short f2bf(float f) {
    unsigned b = __float_as_uint(f);
    return (unsigned short)((b + 0x7fffu + ((b >> 16) & 1u)) >> 16);
}
__device__ __forceinline__ float bf2f(unsigned short h) {
    return __uint_as_float(((unsigned)h) << 16);
}

template <int PX_U8>
__global__ __launch_bounds__(BBLK)
void out_kernel(const int* __restrict__ x, const unsigned* __restrict__ gpx,
                const int* __restrict__ s_in, const float* __restrict__ st,
                float* __restrict__ out) {
    __shared__ unsigned short st_l[65536];         // 128 KB bf16 softmax table
    __shared__ unsigned px_l[CPB_B * 32];          // 16 KB byte-packed x chunk
    __shared__ int s_l[CPB_B];
    const int t = threadIdx.x;

    // stage softmax_table -> bf16 LDS (coalesced)
    const vf4* stv = reinterpret_cast<const vf4*>(st);
    unsigned* stl32 = reinterpret_cast<unsigned*>(st_l);
#pragma unroll 4
    for (int k = 0; k < 32; ++k) {
        const int idx = k * BBLK + t;              // 16384 vf4
        vf4 v = stv[idx];
        unsigned w0 = (unsigned)f2bf(v.x) | ((unsigned)f2bf(v.y) << 16);
        unsigned w1 = (unsigned)f2bf(v.z) | ((unsigned)f2bf(v.w) << 16);
        stl32[idx * 2]     = w0;
        stl32[idx * 2 + 1] = w1;
    }
    __syncthreads();

    for (int c = 0; c < CHUNKS; ++c) {
        const size_t chain0 = ((size_t)blockIdx.x * CHUNKS + c) * CPB_B;

        // stage px chunk (coalesced)
        if (PX_U8) {
#pragma unroll
            for (int k = 0; k < 8; ++k) {
                const int idx = k * BBLK + t;      // 4096 dwords
                px_l[idx] = __builtin_nontemporal_load(&gpx[chain0 * 32 + idx]);
            }
        } else {
            const vi4* xv = reinterpret_cast<const vi4*>(x + chain0 * O_DIM);
#pragma unroll
            for (int k = 0; k < 8; ++k) {
                const int idx = k * BBLK + t;      // 4096 vi4
                vi4 v = __builtin_nontemporal_load(&xv[idx]);
                px_l[idx] = (unsigned)v.x | ((unsigned)v.y << 8) |
                            ((unsigned)v.z << 16) | ((unsigned)v.w << 24);
            }
        }
        if (t < CPB_B) s_l[t] = s_in[chain0 + t];
        __syncthreads();

        // gather from LDS, store coalesced float4
        vf4* ov = reinterpret_cast<vf4*>(out + chain0 * O_DIM);
#pragma unroll 2
        for (int k = 0; k < 8; ++k) {
            const int idx = k * BBLK + t;          // 4096 vf4; idx = chain*32+q
            unsigned p = px_l[idx];
            const int row = s_l[idx >> 5] << 8;
            vf4 r;
            r.x = bf2f(st_l[row + (p & 0xffu)]);
            r.y = bf2f(st_l[row + ((p >> 8) & 0xffu)]);
            r.z = bf2f(st_l[row + ((p >> 16) & 0xffu)]);
            r.w = bf2f(st_l[row + (p >> 24)]);
            __builtin_nontemporal_store(r, &ov[idx]);
        }
        __syncthreads();
    }
}

// ---------------- fallback (round-4 fused kernel, int table) ---------------
__global__ __launch_bounds__(128)
void fused_kernel(const int* __restrict__ x, const int* __restrict__ add_table,
                  const float* __restrict__ st, float* __restrict__ out) {
    __shared__ unsigned px_lds[128 * 32];
    __shared__ int s_lds[128];
    const int t = threadIdx.x;
    const size_t chain0 = (size_t)blockIdx.x * 128;
    const vi4* xv = reinterpret_cast<const vi4*>(x + chain0 * O_DIM);
#pragma unroll 4
    for (int k = 0; k < 32; ++k) {
        const int idx = k * 128 + t;
        vi4 v = __builtin_nontemporal_load(&xv[idx]);
        unsigned p = (unsigned)v.x | ((unsigned)v.y << 8) |
                     ((unsigned)v.z << 16) | ((unsigned)v.w << 24);
        px_lds[(idx >> 5) * 32 + ((idx & 31) ^ ((idx >> 5) & 31))] = p;
    }
    __syncthreads();
    unsigned px[32];
#pragma unroll
    for (int k = 0; k < 32; ++k) px[k] = px_lds[t * 32 + (k ^ (t & 31))];
    int s = 0;
#pragma unroll
    for (int j = 0; j < O_DIM; ++j) {
        unsigned xj = (px[j >> 2] >> ((j & 3) * 8)) & 0xffu;
        s = add_table[((unsigned)j << 16) | ((unsigned)s << 8) | xj];
    }
    s_lds[t] = s;
    __syncthreads();
    vf4* ov = reinterpret_cast<vf4*>(out + chain0 * O_DIM);
#pragma unroll 4
    for (int k = 0; k < 32; ++k) {
        const int idx = k * 128 + t;
        const int chain = idx >> 5, q = idx & 31;
        unsigned p = px_lds[chain * 32 + (q ^ (chain & 31))];
        const float* row = st + ((unsigned)s_lds[chain] << 8);
        vf4 r;
        r.x = row[p & 0xffu]; r.y = row[(p >> 8) & 0xffu];
        r.z = row[(p >> 16) & 0xffu]; r.w = row[p >> 24];
        __builtin_nontemporal_store(r, &ov[idx]);
    }
}

extern "C" void kernel_launch(void* const* d_in, const int* in_sizes, int n_in,
                              void* d_out, int out_size, void* d_ws, size_t ws_size,
                              hipStream_t stream) {
    const int* x         = (const int*)d_in[0];
    const int* add_table = (const int*)d_in[1];
    const float* st      = (const float*)d_in[2];
    float* out           = (float*)d_out;
    char* ws             = (char*)d_ws;

    if (ws_size >= WS_FULL) {
        unsigned char* t8 = (unsigned char*)ws;
        int* s_ws    = (int*)(ws + WS_S);
        unsigned* px = (unsigned*)(ws + WS_PX);
        pack_kernel<<<TAB_ENTRIES / 4 / 256, 256, 0, stream>>>(add_table, t8);
        walk_kernel<1><<<(int)(NCHAINS / ABLK), ABLK, 0, stream>>>(x, t8, s_ws, px);
        out_kernel<1><<<GRID_B, BBLK, 0, stream>>>(x, px, s_ws, st, out);
    } else if (ws_size >= WS_MID) {
        unsigned char* t8 = (unsigned char*)ws;
        int* s_ws = (int*)(ws + WS_S);
        pack_kernel<<<TAB_ENTRIES / 4 / 256, 256, 0, stream>>>(add_table, t8);
        walk_kernel<0><<<(int)(NCHAINS / ABLK), ABLK, 0, stream>>>(x, t8, s_ws, nullptr);
        out_kernel<0><<<GRID_B, BBLK, 0, stream>>>(x, nullptr, s_ws, st, out);
    } else {
        fused_kernel<<<(int)(NCHAINS / 128), 128, 0, stream>>>(x, add_table, st, out);
    }
}

// Round 6
// 203.514 us; speedup vs baseline: 1.7386x; 1.7386x over previous
//
#include <hip/hip_runtime.h>

// WhiteSoftmax: B=8192, C=64, O=128, 256 states, 256 vals.
//   K_pack: add_table int32 -> u8 (8 MB ws).
//   K_walk: 1024 thr x 2 chains = 2048 chains/block, 256 blocks (1/CU).
//           Coalesced x -> byte-pack -> LDS transpose -> px in regs (+ px,s
//           to ws). Walk: per-step 64 KB table slice double-buffered in LDS
//           via global_load_lds(16B) + counted vmcnt(4) + raw s_barrier;
//           state gathers are ds_read_u8 (~5cyc) instead of global (~166cyc).
//   K_out:  unchanged round-5: st bf16 in LDS, px chunks staged, coalesced.

constexpr int O_DIM = 128;
constexpr long long NCHAINS = 8192LL * 64;        // 524288
constexpr int TAB_ENTRIES = 128 * 256 * 256;      // 8 MB u8

constexpr size_t WS_S    = 8u << 20;              // int32 s[NCHAINS] (2 MB)
constexpr size_t WS_PX   = 16u << 20;             // packed px, 128 B/chain (64 MB)
constexpr size_t WS_FULL = 80u << 20;
constexpr size_t WS_MID  = 12u << 20;

typedef int   vi4 __attribute__((ext_vector_type(4)));
typedef float vf4 __attribute__((ext_vector_type(4)));

__global__ __launch_bounds__(256)
void pack_kernel(const int* __restrict__ t32, unsigned char* __restrict__ t8) {
    const int i = (blockIdx.x * 256 + threadIdx.x) * 4;
    vi4 v = *reinterpret_cast<const vi4*>(t32 + i);
    unsigned b = ((unsigned)v.x & 0xffu) | (((unsigned)v.y & 0xffu) << 8) |
                 (((unsigned)v.z & 0xffu) << 16) | (((unsigned)v.w & 0xffu) << 24);
    *reinterpret_cast<unsigned*>(t8 + i) = b;
}

// ---------------- walk kernel: LDS-resident table slices -------------------
constexpr int WBLK = 1024;                        // threads per block
constexpr int WCH  = 2048;                        // chains per block (2/thread)

template <int WRITE_PX>
__global__ __launch_bounds__(WBLK, 4)
void walk_kernel(const int* __restrict__ x, const unsigned char* __restrict__ t8,
                 int* __restrict__ s_out, unsigned* __restrict__ gpx) {
    __shared__ unsigned char slice[2][65536];     // 128 KB double-buffered slice
    unsigned* pxw = reinterpret_cast<unsigned*>(&slice[0][0]);  // 32768 dw scratch

    const int t = threadIdx.x;
    const size_t chain0 = (size_t)blockIdx.x * WCH;

    unsigned px0[32], px1[32];

    // ---- phase 1: two 1024-chain windows: coalesced x load -> pack ->
    //      swizzled LDS transpose -> own-chain regs (+ coalesced px to ws) ----
    auto window = [&](int h, unsigned (&dst)[32]) {
        const vi4* xv = reinterpret_cast<const vi4*>(x + (chain0 + (size_t)h * 1024) * O_DIM);
#pragma unroll 4
        for (int k = 0; k < 32; ++k) {
            const int idx = k * WBLK + t;          // int4 index in window tile
            vi4 v = __builtin_nontemporal_load(&xv[idx]);
            unsigned p = (unsigned)v.x | ((unsigned)v.y << 8) |
                         ((unsigned)v.z << 16) | ((unsigned)v.w << 24);
            const int cl = idx >> 5;               // 32 dwords per chain
            const int d  = idx & 31;
            pxw[cl * 32 + (d ^ (cl & 31))] = p;
        }
        __syncthreads();
#pragma unroll
        for (int k = 0; k < 32; ++k)
            dst[k] = pxw[t * 32 + (k ^ (t & 31))];
        if (WRITE_PX) {
            unsigned* gp = gpx + (chain0 + (size_t)h * 1024) * 32;
#pragma unroll 4
            for (int q = 0; q < 32; ++q) {
                const int idx = q * WBLK + t;
                const int cl = idx >> 5;
                const int d  = idx & 31;
                __builtin_nontemporal_store(pxw[cl * 32 + (d ^ (cl & 31))], &gp[idx]);
            }
        }
        __syncthreads();                           // pxw reads done before reuse
    };
    window(0, px0);
    window(1, px1);

    // ---- phase 2: 128-step walk, LDS slice double-buffer ----
    auto stage = [&](int j, int b) {
        const unsigned char* gsrc = t8 + ((size_t)j << 16);
#pragma unroll
        for (int r = 0; r < 4; ++r) {
            __builtin_amdgcn_global_load_lds(
                (const __attribute__((address_space(1))) void*)(gsrc + r * 16384 + t * 16),
                (__attribute__((address_space(3))) void*)(&slice[b][r * 16384 + t * 16]),
                16, 0, 0);
        }
    };

    stage(0, 0);
    asm volatile("s_waitcnt vmcnt(0)" ::: "memory");   // prologue: slice 0 + phase-1 stores drained
    __builtin_amdgcn_s_barrier();

    int s0 = 0, s1 = 0;
#pragma unroll
    for (int j = 0; j < 127; ++j) {
        stage(j + 1, (j + 1) & 1);                     // issue next slice (4 loads)
        asm volatile("s_waitcnt vmcnt(4)" ::: "memory"); // slice j landed (this wave's share)
        __builtin_amdgcn_s_barrier();                   // all waves' shares landed
        const int buf = j & 1;
        const unsigned xb0 = (px0[j >> 2] >> ((j & 3) * 8)) & 0xffu;
        const unsigned xb1 = (px1[j >> 2] >> ((j & 3) * 8)) & 0xffu;
        s0 = slice[buf][((unsigned)s0 << 8) | xb0];
        s1 = slice[buf][((unsigned)s1 << 8) | xb1];
        asm volatile("s_waitcnt lgkmcnt(0)" ::: "memory"); // my gathers done
        __builtin_amdgcn_s_barrier();                   // all gathers done before buf overwrite
    }
    // j = 127 (no further staging)
    asm volatile("s_waitcnt vmcnt(0)" ::: "memory");
    __builtin_amdgcn_s_barrier();
    {
        const unsigned xb0 = px0[31] >> 24;
        const unsigned xb1 = px1[31] >> 24;
        s0 = slice[1][((unsigned)s0 << 8) | xb0];
        s1 = slice[1][((unsigned)s1 << 8) | xb1];
    }

    s_out[chain0 + t]        = s0;
    s_out[chain0 + 1024 + t] = s1;
}

// ---------------- output kernel: st in LDS as bf16 (round-5) ---------------
constexpr int BBLK = 512;
constexpr int CPB_B = 128;                         // chains per chunk
constexpr int GRID_B = 256;
constexpr int CHUNKS = (int)(NCHAINS / ((long long)GRID_B * CPB_B));  // 16

__device__ __forceinline__ unsigned short f2bf(float f) {
    unsigned b = __float_as_uint(f);
    return (unsigned short)((b + 0x7fffu + ((b >> 16) & 1u)) >> 16);
}
__device__ __forceinline__ float bf2f(unsigned short h) {
    return __uint_as_float(((unsigned)h) << 16);
}

template <int PX_U8>
__global__ __launch_bounds__(BBLK)
void out_kernel(const int* __restrict__ x, const unsigned* __restrict__ gpx,
                const int* __restrict__ s_in, const float* __restrict__ st,
                float* __restrict__ out) {
    __shared__ unsigned short st_l[65536];         // 128 KB bf16 softmax table
    __shared__ unsigned px_l[CPB_B * 32];          // 16 KB byte-packed x chunk
    __shared__ int s_l[CPB_B];
    const int t = threadIdx.x;

    const vf4* stv = reinterpret_cast<const vf4*>(st);
    unsigned* stl32 = reinterpret_cast<unsigned*>(st_l);
#pragma unroll 4
    for (int k = 0; k < 32; ++k) {
        const int idx = k * BBLK + t;              // 16384 vf4
        vf4 v = stv[idx];
        unsigned w0 = (unsigned)f2bf(v.x) | ((unsigned)f2bf(v.y) << 16);
        unsigned w1 = (unsigned)f2bf(v.z) | ((unsigned)f2bf(v.w) << 16);
        stl32[idx * 2]     = w0;
        stl32[idx * 2 + 1] = w1;
    }
    __syncthreads();

    for (int c = 0; c < CHUNKS; ++c) {
        const size_t chain0 = ((size_t)blockIdx.x * CHUNKS + c) * CPB_B;

        if (PX_U8) {
#pragma unroll
            for (int k = 0; k < 8; ++k) {
                const int idx = k * BBLK + t;      // 4096 dwords
                px_l[idx] = __builtin_nontemporal_load(&gpx[chain0 * 32 + idx]);
            }
        } else {
            const vi4* xv = reinterpret_cast<const vi4*>(x + chain0 * O_DIM);
#pragma unroll
            for (int k = 0; k < 8; ++k) {
                const int idx = k * BBLK + t;      // 4096 vi4
                vi4 v = __builtin_nontemporal_load(&xv[idx]);
                px_l[idx] = (unsigned)v.x | ((unsigned)v.y << 8) |
                            ((unsigned)v.z << 16) | ((unsigned)v.w << 24);
            }
        }
        if (t < CPB_B) s_l[t] = s_in[chain0 + t];
        __syncthreads();

        vf4* ov = reinterpret_cast<vf4*>(out + chain0 * O_DIM);
#pragma unroll 2
        for (int k = 0; k < 8; ++k) {
            const int idx = k * BBLK + t;          // 4096 vf4; idx = chain*32+q
            unsigned p = px_l[idx];
            const int row = s_l[idx >> 5] << 8;
            vf4 r;
            r.x = bf2f(st_l[row + (p & 0xffu)]);
            r.y = bf2f(st_l[row + ((p >> 8) & 0xffu)]);
            r.z = bf2f(st_l[row + ((p >> 16) & 0xffu)]);
            r.w = bf2f(st_l[row + (p >> 24)]);
            __builtin_nontemporal_store(r, &ov[idx]);
        }
        __syncthreads();
    }
}

// ---------------- fallback (round-4 fused kernel, int table) ---------------
__global__ __launch_bounds__(128)
void fused_kernel(const int* __restrict__ x, const int* __restrict__ add_table,
                  const float* __restrict__ st, float* __restrict__ out) {
    __shared__ unsigned px_lds[128 * 32];
    __shared__ int s_lds[128];
    const int t = threadIdx.x;
    const size_t chain0 = (size_t)blockIdx.x * 128;
    const vi4* xv = reinterpret_cast<const vi4*>(x + chain0 * O_DIM);
#pragma unroll 4
    for (int k = 0; k < 32; ++k) {
        const int idx = k * 128 + t;
        vi4 v = __builtin_nontemporal_load(&xv[idx]);
        unsigned p = (unsigned)v.x | ((unsigned)v.y << 8) |
                     ((unsigned)v.z << 16) | ((unsigned)v.w << 24);
        px_lds[(idx >> 5) * 32 + ((idx & 31) ^ ((idx >> 5) & 31))] = p;
    }
    __syncthreads();
    unsigned px[32];
#pragma unroll
    for (int k = 0; k < 32; ++k) px[k] = px_lds[t * 32 + (k ^ (t & 31))];
    int s = 0;
#pragma unroll
    for (int j = 0; j < O_DIM; ++j) {
        unsigned xj = (px[j >> 2] >> ((j & 3) * 8)) & 0xffu;
        s = add_table[((unsigned)j << 16) | ((unsigned)s << 8) | xj];
    }
    s_lds[t] = s;
    __syncthreads();
    vf4* ov = reinterpret_cast<vf4*>(out + chain0 * O_DIM);
#pragma unroll 4
    for (int k = 0; k < 32; ++k) {
        const int idx = k * 128 + t;
        const int chain = idx >> 5, q = idx & 31;
        unsigned p = px_lds[chain * 32 + (q ^ (chain & 31))];
        const float* row = st + ((unsigned)s_lds[chain] << 8);
        vf4 r;
        r.x = row[p & 0xffu]; r.y = row[(p >> 8) & 0xffu];
        r.z = row[(p >> 16) & 0xffu]; r.w = row[p >> 24];
        __builtin_nontemporal_store(r, &ov[idx]);
    }
}

extern "C" void kernel_launch(void* const* d_in, const int* in_sizes, int n_in,
                              void* d_out, int out_size, void* d_ws, size_t ws_size,
                              hipStream_t stream) {
    const int* x         = (const int*)d_in[0];
    const int* add_table = (const int*)d_in[1];
    const float* st      = (const float*)d_in[2];
    float* out           = (float*)d_out;
    char* ws             = (char*)d_ws;

    if (ws_size >= WS_FULL) {
        unsigned char* t8 = (unsigned char*)ws;
        int* s_ws    = (int*)(ws + WS_S);
        unsigned* px = (unsigned*)(ws + WS_PX);
        pack_kernel<<<TAB_ENTRIES / 4 / 256, 256, 0, stream>>>(add_table, t8);
        walk_kernel<1><<<(int)(NCHAINS / WCH), WBLK, 0, stream>>>(x, t8, s_ws, px);
        out_kernel<1><<<GRID_B, BBLK, 0, stream>>>(x, px, s_ws, st, out);
    } else if (ws_size >= WS_MID) {
        unsigned char* t8 = (unsigned char*)ws;
        int* s_ws = (int*)(ws + WS_S);
        pack_kernel<<<TAB_ENTRIES / 4 / 256, 256, 0, stream>>>(add_table, t8);
        walk_kernel<0><<<(int)(NCHAINS / WCH), WBLK, 0, stream>>>(x, t8, s_ws, nullptr);
        out_kernel<0><<<GRID_B, BBLK, 0, stream>>>(x, nullptr, s_ws, st, out);
    } else {
        fused_kernel<<<(int)(NCHAINS / 128), 128, 0, stream>>>(x, add_table, st, out);
    }
}

// Round 7
// 185.229 us; speedup vs baseline: 1.9102x; 1.0987x over previous
//
#include <hip/hip_runtime.h>

// WhiteSoftmax: B=8192, C=64, O=128, 256 states, 256 vals.
//   K_pack:  add_table int32 -> u8 (8 MB ws).
//   K_fused: 1024 thr x 2 chains = 2048 chains/block, 256 blocks (1/CU).
//     phase 1: coalesced x -> byte-pack -> LDS transpose -> px0/px1 regs.
//     phase 2: 128-step walk; per-step 64 KB u8 table slice double-buffered
//              in LDS via global_load_lds(16B) + counted vmcnt(4) + s_barrier;
//              state gathers are ds_read_u8 (~8cyc) not global (~166cyc).
//     phase 3: restage softmax_table as bf16 into the dead slice LDS (128 KB);
//              16 chunks x 128 chains: owner threads deposit px+s to scratch,
//              all waves gather from LDS + coalesced nontemporal float4 store.
//   No px/s workspace round-trip; no walk->out kernel boundary.

constexpr int O_DIM = 128;
constexpr long long NCHAINS = 8192LL * 64;        // 524288
constexpr int TAB_ENTRIES = 128 * 256 * 256;      // 8 MB u8

typedef int   vi4 __attribute__((ext_vector_type(4)));
typedef float vf4 __attribute__((ext_vector_type(4)));

__global__ __launch_bounds__(256)
void pack_kernel(const int* __restrict__ t32, unsigned char* __restrict__ t8) {
    const int i = (blockIdx.x * 256 + threadIdx.x) * 4;
    vi4 v = *reinterpret_cast<const vi4*>(t32 + i);
    unsigned b = ((unsigned)v.x & 0xffu) | (((unsigned)v.y & 0xffu) << 8) |
                 (((unsigned)v.z & 0xffu) << 16) | (((unsigned)v.w & 0xffu) << 24);
    *reinterpret_cast<unsigned*>(t8 + i) = b;
}

__device__ __forceinline__ unsigned f2bf(float f) {
    unsigned b = __float_as_uint(f);
    return (b + 0x7fffu + ((b >> 16) & 1u)) >> 16;
}
__device__ __forceinline__ float bf2f(unsigned short h) {
    return __uint_as_float(((unsigned)h) << 16);
}

constexpr int WBLK = 1024;                        // threads per block
constexpr int WCH  = 2048;                        // chains per block (2/thread)

__global__ __launch_bounds__(WBLK, 4)
void fused_ws(const int* __restrict__ x, const unsigned char* __restrict__ t8,
              const float* __restrict__ st, float* __restrict__ out) {
    __shared__ unsigned char slice[2][65536];     // walk slices / phase-1 scratch / st bf16
    __shared__ unsigned px_out[128 * 32];         // 16 KB output px scratch
    __shared__ int s_l[128];
    unsigned* pxw = reinterpret_cast<unsigned*>(&slice[0][0]);

    const int t = threadIdx.x;
    const size_t chain0 = (size_t)blockIdx.x * WCH;

    unsigned px0[32], px1[32];

    // ---- phase 1: two 1024-chain windows: coalesced x load -> pack ->
    //      swizzled LDS transpose -> own-chain regs ----
    auto window = [&](int h, unsigned (&dst)[32]) {
        const vi4* xv = reinterpret_cast<const vi4*>(x + (chain0 + (size_t)h * 1024) * O_DIM);
#pragma unroll 4
        for (int k = 0; k < 32; ++k) {
            const int idx = k * WBLK + t;          // int4 index in window tile
            vi4 v = __builtin_nontemporal_load(&xv[idx]);
            unsigned p = (unsigned)v.x | ((unsigned)v.y << 8) |
                         ((unsigned)v.z << 16) | ((unsigned)v.w << 24);
            const int cl = idx >> 5;               // 32 dwords per chain
            const int d  = idx & 31;
            pxw[cl * 32 + (d ^ (cl & 31))] = p;
        }
        __syncthreads();
#pragma unroll
        for (int k = 0; k < 32; ++k)
            dst[k] = pxw[t * 32 + (k ^ (t & 31))];
        __syncthreads();                           // pxw reads done before reuse
    };
    window(0, px0);
    window(1, px1);

    // ---- phase 2: 128-step walk, LDS slice double-buffer ----
    auto stage = [&](int j, int b) {
        const unsigned char* gsrc = t8 + ((size_t)j << 16);
#pragma unroll
        for (int r = 0; r < 4; ++r) {
            __builtin_amdgcn_global_load_lds(
                (const __attribute__((address_space(1))) void*)(gsrc + r * 16384 + t * 16),
                (__attribute__((address_space(3))) void*)(&slice[b][r * 16384 + t * 16]),
                16, 0, 0);
        }
    };

    stage(0, 0);
    asm volatile("s_waitcnt vmcnt(0)" ::: "memory");
    __builtin_amdgcn_s_barrier();

    int s0 = 0, s1 = 0;
#pragma unroll
    for (int j = 0; j < 127; ++j) {
        stage(j + 1, (j + 1) & 1);                     // issue next slice
        asm volatile("s_waitcnt vmcnt(4)" ::: "memory"); // slice j landed (my share)
        __builtin_amdgcn_s_barrier();                   // all waves' shares landed
        const int buf = j & 1;
        const unsigned xb0 = (px0[j >> 2] >> ((j & 3) * 8)) & 0xffu;
        const unsigned xb1 = (px1[j >> 2] >> ((j & 3) * 8)) & 0xffu;
        s0 = slice[buf][((unsigned)s0 << 8) | xb0];
        s1 = slice[buf][((unsigned)s1 << 8) | xb1];
        asm volatile("s_waitcnt lgkmcnt(0)" ::: "memory"); // my gathers done
        __builtin_amdgcn_s_barrier();                   // all gathers done before overwrite
    }
    asm volatile("s_waitcnt vmcnt(0)" ::: "memory");
    __builtin_amdgcn_s_barrier();
    {
        const unsigned xb0 = px0[31] >> 24;
        const unsigned xb1 = px1[31] >> 24;
        s0 = slice[1][((unsigned)s0 << 8) | xb0];
        s1 = slice[1][((unsigned)s1 << 8) | xb1];
    }
    __syncthreads();                                    // final gathers done, slices dead

    // ---- phase 3: st -> bf16 in slice LDS, chunked coalesced output ----
    unsigned* stl32 = reinterpret_cast<unsigned*>(&slice[0][0]);
    unsigned short* st_l = reinterpret_cast<unsigned short*>(&slice[0][0]);
    const vf4* stv = reinterpret_cast<const vf4*>(st);
#pragma unroll 4
    for (int k = 0; k < 16; ++k) {
        const int idx = k * WBLK + t;              // 16384 vf4 = 64K floats
        vf4 v = stv[idx];
        stl32[idx * 2]     = f2bf(v.x) | (f2bf(v.y) << 16);
        stl32[idx * 2 + 1] = f2bf(v.z) | (f2bf(v.w) << 16);
    }
    __syncthreads();

    auto do_chunks = [&](const unsigned (&pp)[32], int sreg, int w) {
        for (int c = 0; c < 8; ++c) {
            if ((t >> 7) == c) {                   // owner threads deposit px + s
                const int lc = t & 127;
                s_l[lc] = sreg;
#pragma unroll
                for (int k = 0; k < 32; ++k)
                    px_out[lc * 32 + (k ^ (lc & 31))] = pp[k];
            }
            __syncthreads();
            vf4* ov = reinterpret_cast<vf4*>(
                out + (chain0 + (size_t)w * 1024 + (size_t)c * 128) * O_DIM);
#pragma unroll
            for (int k = 0; k < 4; ++k) {
                const int idx = k * WBLK + t;      // 4096 vf4 per chunk
                const int cl = idx >> 5, q = idx & 31;
                unsigned p = px_out[cl * 32 + (q ^ (cl & 31))];
                const int row = s_l[cl] << 8;
                vf4 r;
                r.x = bf2f((unsigned short)st_l[row + (p & 0xffu)]);
                r.y = bf2f((unsigned short)st_l[row + ((p >> 8) & 0xffu)]);
                r.z = bf2f((unsigned short)st_l[row + ((p >> 16) & 0xffu)]);
                r.w = bf2f((unsigned short)st_l[row + (p >> 24)]);
                __builtin_nontemporal_store(r, &ov[idx]);
            }
            __syncthreads();
        }
    };
    do_chunks(px0, s0, 0);
    do_chunks(px1, s1, 1);
}

// ---------------- fallback (no-ws fused kernel, f32 table) -----------------
__global__ __launch_bounds__(128)
void fused_kernel(const int* __restrict__ x, const int* __restrict__ add_table,
                  const float* __restrict__ st, float* __restrict__ out) {
    __shared__ unsigned px_lds[128 * 32];
    __shared__ int s_lds[128];
    const int t = threadIdx.x;
    const size_t chain0 = (size_t)blockIdx.x * 128;
    const vi4* xv = reinterpret_cast<const vi4*>(x + chain0 * O_DIM);
#pragma unroll 4
    for (int k = 0; k < 32; ++k) {
        const int idx = k * 128 + t;
        vi4 v = __builtin_nontemporal_load(&xv[idx]);
        unsigned p = (unsigned)v.x | ((unsigned)v.y << 8) |
                     ((unsigned)v.z << 16) | ((unsigned)v.w << 24);
        px_lds[(idx >> 5) * 32 + ((idx & 31) ^ ((idx >> 5) & 31))] = p;
    }
    __syncthreads();
    unsigned px[32];
#pragma unroll
    for (int k = 0; k < 32; ++k) px[k] = px_lds[t * 32 + (k ^ (t & 31))];
    int s = 0;
#pragma unroll
    for (int j = 0; j < O_DIM; ++j) {
        unsigned xj = (px[j >> 2] >> ((j & 3) * 8)) & 0xffu;
        s = add_table[((unsigned)j << 16) | ((unsigned)s << 8) | xj];
    }
    s_lds[t] = s;
    __syncthreads();
    vf4* ov = reinterpret_cast<vf4*>(out + chain0 * O_DIM);
#pragma unroll 4
    for (int k = 0; k < 32; ++k) {
        const int idx = k * 128 + t;
        const int chain = idx >> 5, q = idx & 31;
        unsigned p = px_lds[chain * 32 + (q ^ (chain & 31))];
        const float* row = st + ((unsigned)s_lds[chain] << 8);
        vf4 r;
        r.x = row[p & 0xffu]; r.y = row[(p >> 8) & 0xffu];
        r.z = row[(p >> 16) & 0xffu]; r.w = row[p >> 24];
        __builtin_nontemporal_store(r, &ov[idx]);
    }
}

extern "C" void kernel_launch(void* const* d_in, const int* in_sizes, int n_in,
                              void* d_out, int out_size, void* d_ws, size_t ws_size,
                              hipStream_t stream) {
    const int* x         = (const int*)d_in[0];
    const int* add_table = (const int*)d_in[1];
    const float* st      = (const float*)d_in[2];
    float* out           = (float*)d_out;

    if (ws_size >= (size_t)TAB_ENTRIES) {
        unsigned char* t8 = (unsigned char*)d_ws;
        pack_kernel<<<TAB_ENTRIES / 4 / 256, 256, 0, stream>>>(add_table, t8);
        fused_ws<<<(int)(NCHAINS / WCH), WBLK, 0, stream>>>(x, t8, st, out);
    } else {
        fused_kernel<<<(int)(NCHAINS / 128), 128, 0, stream>>>(x, add_table, st, out);
    }
}